// Round 24
// baseline (566.765 us; speedup 1.0000x reference)
//
#include <hip/hip_runtime.h>
#include <hip/hip_bf16.h>

// Problem constants
#define B_   2
#define S_   2048
#define D_   4096
#define H_   32
#define HKV_ 8
#define HD_  128
#define QKVS 6144   // fused QKV row stride (H*HD + 2*HKV*HD)

typedef __bf16 bf16;
typedef __bf16 bf16x8 __attribute__((ext_vector_type(8)));
typedef __bf16 bf16x4 __attribute__((ext_vector_type(4)));
typedef __bf16 bf16x2 __attribute__((ext_vector_type(2)));
typedef float  f32x4  __attribute__((ext_vector_type(4)));
typedef float  f32x16 __attribute__((ext_vector_type(16)));
typedef unsigned int u32x4 __attribute__((ext_vector_type(4)));

// ---------------- prep kernels ----------------

__global__ void cast_f32_bf16_kernel(const float* __restrict__ in, bf16* __restrict__ out, int n) {
    int i = (blockIdx.x * blockDim.x + threadIdx.x) * 4;
    if (i >= n) return;
    const float4 v = *(const float4*)(in + i);
    bf16x4 o;
    o[0] = (bf16)v.x; o[1] = (bf16)v.y; o[2] = (bf16)v.z; o[3] = (bf16)v.w;
    *(bf16x4*)(out + i) = o;
}

// W: K x N fp32 row-major -> WT: N x K bf16 row-major. 64x64 tile, 256 thr.
__global__ __launch_bounds__(256) void transpose_cast_kernel(const float* __restrict__ W,
                                                             bf16* __restrict__ WT, int K, int N) {
    __shared__ bf16 t[64][65];
    const int n0 = blockIdx.x * 64, k0 = blockIdx.y * 64;
    const int tx = threadIdx.x & 15, ty = threadIdx.x >> 4;   // 16 x 16
    #pragma unroll
    for (int i = 0; i < 4; i++) {
        const float4 v = *(const float4*)(W + (size_t)(k0 + ty + i * 16) * N + n0 + tx * 4);
        t[ty + i * 16][tx * 4 + 0] = (bf16)v.x;
        t[ty + i * 16][tx * 4 + 1] = (bf16)v.y;
        t[ty + i * 16][tx * 4 + 2] = (bf16)v.z;
        t[ty + i * 16][tx * 4 + 3] = (bf16)v.w;
    }
    __syncthreads();
    #pragma unroll
    for (int i = 0; i < 4; i++) {
        bf16x4 o;
        #pragma unroll
        for (int j = 0; j < 4; j++) o[j] = t[tx * 4 + j][ty + i * 16];
        *(bf16x4*)(WT + (size_t)(n0 + ty + i * 16) * K + k0 + tx * 4) = o;
    }
}

// V (cols 5120.. of QKV, row stride QKVS) -> Vt: (b,hk,d) x s bf16. 64x64 tile.
__global__ __launch_bounds__(256) void transpose_v_kernel(const bf16* __restrict__ V,
                                                          bf16* __restrict__ Vt) {
    __shared__ bf16 t[64][65];
    const int bh = blockIdx.z;            // b*HKV + hk
    const int b = bh >> 3, hk = bh & 7;
    const int d0 = blockIdx.x * 64, s0 = blockIdx.y * 64;
    const int tx = threadIdx.x & 15, ty = threadIdx.x >> 4;
    #pragma unroll
    for (int i = 0; i < 4; i++) {
        const bf16x4 v = *(const bf16x4*)(V + (size_t)(b * S_ + s0 + ty + i * 16) * QKVS + hk * HD_ + d0 + tx * 4);
        #pragma unroll
        for (int j = 0; j < 4; j++) t[ty + i * 16][tx * 4 + j] = v[j];   // t[s][d]
    }
    __syncthreads();
    #pragma unroll
    for (int i = 0; i < 4; i++) {
        bf16x4 o;
        #pragma unroll
        for (int j = 0; j < 4; j++) o[j] = t[tx * 4 + j][ty + i * 16];
        *(bf16x4*)(Vt + (size_t)(bh * HD_ + d0 + ty + i * 16) * S_ + s0 + tx * 4) = o;
    }
}

// rotate-half RoPE in place; used for K only (nh=8), Q is fused into attn.
__global__ void rope_kernel(bf16* __restrict__ T, int nh, int stride) {
    const int row = blockIdx.x;
    const int pos = row & (S_ - 1);
    const size_t base = (size_t)row * stride;
    const int npairs = nh * 64;
    const float c = 13.287712379549449f / 64.0f;   // log2(10000)/64
    for (int p = threadIdx.x; p < npairs; p += blockDim.x) {
        const int h = p >> 6, d = p & 63;
        const float invf = exp2f(-(float)d * c);
        const float ang = (float)pos * invf;
        float sn, cs;
        sincosf(ang, &sn, &cs);
        const size_t i1 = base + (size_t)h * HD_ + d;
        const size_t i2 = i1 + 64;
        const float a  = (float)T[i1];
        const float b2 = (float)T[i2];
        T[i1] = (bf16)(a * cs - b2 * sn);
        T[i2] = (bf16)(b2 * cs + a * sn);
    }
}

__device__ __forceinline__ void gload_lds16(const bf16* g, bf16* l) {
    __builtin_amdgcn_global_load_lds((const __attribute__((address_space(1))) void*)g,
                                     (__attribute__((address_space(3))) void*)l, 16, 0, 0);
}

// ---------------- GEMM 128x128 (m97 structure) — KV projection ----------------

template <typename CT>
__global__ __launch_bounds__(256) void gemm_bt_kernel(const bf16* __restrict__ A,
                                                      const bf16* __restrict__ Bm,
                                                      CT* __restrict__ C,
                                                      int M, int Cs, int K) {
    __shared__ bf16 As[128 * 32];
    __shared__ bf16 Bs[128 * 32];
    const int m0 = blockIdx.x * 128, n0 = blockIdx.y * 128;
    const int tid = threadIdx.x;
    const int lane = tid & 63, wid = tid >> 6;
    const int wm = wid >> 1, wn = wid & 1;       // 2x2 waves -> 64x64 each
    const int lg = lane >> 4, lr = lane & 15;
    f32x4 acc[4][4] = {};
    const int arow = tid >> 2;
    const int achunk = (tid & 3) * 8;
    for (int k0 = 0; k0 < K; k0 += 32) {
        gload_lds16(A  + (size_t)(m0 + arow) * K      + k0 + achunk, As + tid * 8);
        gload_lds16(A  + (size_t)(m0 + 64 + arow) * K + k0 + achunk, As + 2048 + tid * 8);
        gload_lds16(Bm + (size_t)(n0 + arow) * K      + k0 + achunk, Bs + tid * 8);
        gload_lds16(Bm + (size_t)(n0 + 64 + arow) * K + k0 + achunk, Bs + 2048 + tid * 8);
        __syncthreads();
        bf16x8 af[4], bfv[4];
        #pragma unroll
        for (int i = 0; i < 4; i++) {
            af[i]  = *(const bf16x8*)(As + (wm * 64 + i * 16 + lr) * 32 + lg * 8);
            bfv[i] = *(const bf16x8*)(Bs + (wn * 64 + i * 16 + lr) * 32 + lg * 8);
        }
        #pragma unroll
        for (int mi = 0; mi < 4; mi++)
            #pragma unroll
            for (int ni = 0; ni < 4; ni++)
                acc[mi][ni] = __builtin_amdgcn_mfma_f32_16x16x32_bf16(af[mi], bfv[ni], acc[mi][ni], 0, 0, 0);
        __syncthreads();
    }
    #pragma unroll
    for (int mi = 0; mi < 4; mi++)
        #pragma unroll
        for (int ni = 0; ni < 4; ni++)
            #pragma unroll
            for (int r = 0; r < 4; r++) {
                const int row = m0 + wm * 64 + mi * 16 + lg * 4 + r;
                const int col = n0 + wn * 64 + ni * 16 + lr;
                C[(size_t)row * Cs + col] = (CT)acc[mi][ni][r];
            }
}

// ---------------- GEMM 256x256, BK=64, 8 waves, 4-phase pipelined + quadrant reg-cache ----

template <typename CT>
__global__ __launch_bounds__(512, 2) void gemm_bt256_kernel(const bf16* __restrict__ A,
                                                            const bf16* __restrict__ Bm,
                                                            CT* __restrict__ C,
                                                            int M, int N, int K, int Cs) {
    __shared__ bf16 sm[65536];   // 128 KiB
    const int nbx = N >> 8;
    const int cpx = gridDim.x >> 3;
    const int bid = blockIdx.x;
    const int swz = (bid & 7) * cpx + (bid >> 3);       // XCD swizzle (grid % 8 == 0)
    const int m0 = (swz / nbx) << 8;
    const int n0 = (swz % nbx) << 8;

    const int tid = threadIdx.x;
    const int w = tid >> 6, lane = tid & 63;
    const int wm = w >> 2, wn = w & 3;                  // 2 x 4 wave grid, 128x64 per wave
    const int lg = lane >> 4, lr = lane & 15;
    const int nkt = K >> 6;

    const bf16* Ab = A + (size_t)m0 * K;
    const bf16* Bb = Bm + (size_t)n0 * K;

    const int u8 = tid >> 3;
    const int schunk = ((tid & 7) ^ (u8 & 7)) << 3;     // pre-swizzled source col offset

    auto stageA = [&](int buf, int kt, int h) {
        bf16* dst = sm + buf * 32768 + h * 4096 + tid * 8;
        const bf16* src = Ab + (size_t)(h * 64 + u8) * K + kt * 64 + schunk;
        gload_lds16(src, dst);
        gload_lds16(src + (size_t)128 * K, dst + 8192);
    };
    auto stageB = [&](int buf, int kt, int h) {
        bf16* dst = sm + buf * 32768 + 16384 + h * 2048 + ((u8 >> 5) << 12) + ((u8 & 31) << 6) + ((tid & 7) << 3);
        const bf16* src = Bb + (size_t)(h * 32 + ((u8 >> 5) << 6) + (u8 & 31)) * K + kt * 64 + schunk;
        gload_lds16(src, dst);
        gload_lds16(src + (size_t)128 * K, dst + 8192);
    };

    f32x4 acc[8][4] = {};

    // prologue: tile0 fully -> buf0 (8 loads); tile1 B0,A0 -> buf1 (4 loads)
    stageA(0, 0, 0); stageA(0, 0, 1); stageB(0, 0, 0); stageB(0, 0, 1);
    stageB(1, 1, 0); stageA(1, 1, 0);
    asm volatile("s_waitcnt vmcnt(4)" ::: "memory");    // tile0 landed; tile1's 4 in flight
    __builtin_amdgcn_s_barrier();

    #define MFMA_Q(MI0, NI0, AREG, BREG)                                                     \
        __builtin_amdgcn_s_setprio(1);                                                       \
        _Pragma("unroll") for (int i = 0; i < 4; ++i)                                        \
            _Pragma("unroll") for (int i2 = 0; i2 < 2; ++i2)                                 \
                _Pragma("unroll") for (int kk = 0; kk < 2; ++kk)                             \
                    acc[MI0 + i][NI0 + i2] = __builtin_amdgcn_mfma_f32_16x16x32_bf16(        \
                        AREG[i][kk], BREG[i2][kk], acc[MI0 + i][NI0 + i2], 0, 0, 0);         \
        __builtin_amdgcn_s_setprio(0);                                                       \
        __builtin_amdgcn_s_barrier();

    #define SYNC_IN()                                                                        \
        __builtin_amdgcn_s_barrier();                                                        \
        asm volatile("s_waitcnt lgkmcnt(0)" ::: "memory");                                   \
        __builtin_amdgcn_sched_barrier(0);

    for (int t = 0; t < nkt; ++t) {
        const int cur = t & 1;
        const bf16* curA = sm + cur * 32768;
        const bf16* curB = curA + 16384;
        bf16x8 afc[4][2], b0[2][2], b1[2][2];

        // ---- Phase A: (0,0). Read+cache A-quad0, B-quad0. Stage A1(t+1)->other.
        #pragma unroll
        for (int i = 0; i < 4; ++i) {
            const int row = wm * 128 + i * 16 + lr;
            #pragma unroll
            for (int kk = 0; kk < 2; ++kk)
                afc[i][kk] = *(const bf16x8*)(curA + row * 64 + (((kk * 4 + lg) ^ (lr & 7)) << 3));
        }
        #pragma unroll
        for (int i2 = 0; i2 < 2; ++i2) {
            const int row = wn * 64 + i2 * 16 + lr;
            #pragma unroll
            for (int kk = 0; kk < 2; ++kk)
                b0[i2][kk] = *(const bf16x8*)(curB + row * 64 + (((kk * 4 + lg) ^ (lr & 7)) << 3));
        }
        if (t + 1 < nkt) stageA(cur ^ 1, t + 1, 1);
        if (t + 1 == nkt) asm volatile("s_waitcnt vmcnt(0)" ::: "memory");  // final-tile drain
        SYNC_IN()
        MFMA_Q(0, 0, afc, b0)

        // ---- Phase B: (0,1). Read+cache B-quad1. Stage B1(t+1)->other.
        #pragma unroll
        for (int i2 = 0; i2 < 2; ++i2) {
            const int row = wn * 64 + (2 + i2) * 16 + lr;
            #pragma unroll
            for (int kk = 0; kk < 2; ++kk)
                b1[i2][kk] = *(const bf16x8*)(curB + row * 64 + (((kk * 4 + lg) ^ (lr & 7)) << 3));
        }
        if (t + 1 < nkt) stageB(cur ^ 1, t + 1, 1);
        SYNC_IN()
        MFMA_Q(0, 2, afc, b1)

        // ---- Phase C: (1,0). Read A-quad1 (overwrite cache); b0 still cached. Stage B0(t+2)->cur.
        #pragma unroll
        for (int i = 0; i < 4; ++i) {
            const int row = wm * 128 + (4 + i) * 16 + lr;
            #pragma unroll
            for (int kk = 0; kk < 2; ++kk)
                afc[i][kk] = *(const bf16x8*)(curA + row * 64 + (((kk * 4 + lg) ^ (lr & 7)) << 3));
        }
        if (t + 2 < nkt) stageB(cur, t + 2, 0);
        SYNC_IN()
        MFMA_Q(4, 0, afc, b0)

        // ---- Phase D: (1,1). No LDS reads (afc=A1, b1 cached). Stage A0(t+2)->cur; counted wait.
        if (t + 2 < nkt) stageA(cur, t + 2, 0);
        asm volatile("s_waitcnt vmcnt(4)" ::: "memory");
        SYNC_IN()
        MFMA_Q(4, 2, afc, b1)
    }
    #undef MFMA_Q
    #undef SYNC_IN

    #pragma unroll
    for (int mi = 0; mi < 8; ++mi)
        #pragma unroll
        for (int ni = 0; ni < 4; ++ni)
            #pragma unroll
            for (int r = 0; r < 4; ++r) {
                const int row = m0 + wm * 128 + mi * 16 + lg * 4 + r;
                const int col = n0 + wn * 64 + ni * 16 + lr;
                C[(size_t)row * Cs + col] = (CT)acc[mi][ni][r];
            }
}

// ---------------- flash attention — 32x32x16 MFMA, swapped QK^T, in-register P,
// rope-Q fused into the prologue (Q read once, only by this kernel) ----------------
#define KVB_ 64

__device__ __forceinline__ unsigned int pkbf(float lo, float hi2) {
    bf16x2 t; t[0] = (bf16)lo; t[1] = (bf16)hi2;
    return __builtin_bit_cast(unsigned int, t);
}

__global__ __launch_bounds__(256) void attn_kernel(const bf16* __restrict__ Q,
                                                   const bf16* __restrict__ Kb,
                                                   const bf16* __restrict__ Vt,
                                                   bf16* __restrict__ O) {
    __shared__ bf16 lds[16384];   // Ks[64][128] | Vs[128][64]  (32 KiB)
    bf16* Ks = lds;
    bf16* Vs = lds + 8192;

    const int flat = blockIdx.x;
    const int x = flat & 7;
    const int j = flat >> 3;
    const int hkb = x * 2 + (j & 1);
    const int qt = 63 - (j >> 1);
    const int hk = hkb & 7, b = hkb >> 3;
    const int q0 = qt * 32;

    const int tid = threadIdx.x;
    const int w = tid >> 6, lane = tid & 63;
    const int l31 = lane & 31, hi = lane >> 5;
    const int h = hk * 4 + w;

    // Q fragments (B-operand): col q = q0+l31, hd = t*16 + hi*8 + j
    const bf16* qrow = Q + ((size_t)(b * S_ + q0 + l31)) * QKVS + h * HD_ + hi * 8;
    bf16x8 qf[8];
    #pragma unroll
    for (int t = 0; t < 8; t++) qf[t] = *(const bf16x8*)(qrow + t * 16);

    // ---- fused rotate-half RoPE on Q (pos = q0+l31; pair d <-> d+64 = qf[t] <-> qf[t+4]) ----
    {
        const float c2 = 13.287712379549449f / 64.0f;   // log2(10000)/64
        const float posf = (float)(q0 + l31);
        #pragma unroll
        for (int t = 0; t < 4; t++) {
            #pragma unroll
            for (int jj = 0; jj < 8; jj++) {
                const int d = t * 16 + hi * 8 + jj;     // < 64
                float sn, cs;
                sincosf(posf * exp2f(-(float)d * c2), &sn, &cs);
                const float lo = (float)qf[t][jj], up = (float)qf[t + 4][jj];
                qf[t][jj]     = (bf16)(lo * cs - up * sn);
                qf[t + 4][jj] = (bf16)(up * cs + lo * sn);
            }
        }
    }

    const bf16* Kh = Kb + ((size_t)b * S_) * QKVS + hk * HD_;
    const bf16* Vh = Vt + ((size_t)(b * HKV_ + hk)) * HD_ * S_;

    const int krow_s  = tid >> 4;
    const int kchnk_s = (tid & 15) ^ (tid >> 4);
    const int vrow_s  = tid >> 3;
    const int vchnk_s = (tid & 7) ^ ((tid >> 3) & 7);

    f32x16 acc[4];
    #pragma unroll
    for (int dt = 0; dt < 4; dt++) acc[dt] = (f32x16)(0.f);
    float rowmax = -1e30f, rowsum = 0.f;

    const float scale = 0.08838834764831845f;
    const int nt = (q0 + 32 + KVB_ - 1) / KVB_;
    const int qg = q0 + l31;

    for (int it = 0; it < nt; ++it) {
        const int k0 = it * KVB_;
        #pragma unroll
        for (int jj = 0; jj < 4; jj++)
            gload_lds16(Kh + (size_t)(k0 + jj * 16 + krow_s) * QKVS + kchnk_s * 8,
                        Ks + jj * 2048 + tid * 8);
        #pragma unroll
        for (int jj = 0; jj < 4; jj++)
            gload_lds16(Vh + (size_t)(jj * 32 + vrow_s) * S_ + k0 + vchnk_s * 8,
                        Vs + jj * 2048 + tid * 8);
        __syncthreads();

        // ---- QK^T swapped: st0/st1 = mfma(K_sub, Q) -> D[k][q=l31] ----
        f32x16 st0 = (f32x16)(0.f), st1 = (f32x16)(0.f);
        #pragma unroll
        for (int t = 0; t < 8; t++) {
            const int ch = (((2 * t + hi) ^ (l31 & 15)) << 3);
            const bf16x8 kf0 = *(const bf16x8*)(Ks + l31 * 128 + ch);
            const bf16x8 kf1 = *(const bf16x8*)(Ks + (32 + l31) * 128 + ch);
            st0 = __builtin_amdgcn_mfma_f32_32x32x16_bf16(kf0, qf[t], st0, 0, 0, 0);
            st1 = __builtin_amdgcn_mfma_f32_32x32x16_bf16(kf1, qf[t], st1, 0, 0, 0);
        }

        // ---- scale + causal mask: k = k0 + kt*32 + (r&3)+8*(r>>2)+4*hi, q = qg ----
        const bool need_mask = (k0 + KVB_ - 1 > q0);
        #pragma unroll
        for (int r = 0; r < 16; r++) {
            const int kr = (r & 3) + 8 * (r >> 2) + 4 * hi;
            float s0 = st0[r] * scale;
            float s1 = st1[r] * scale;
            if (need_mask) {
                s0 = (k0 + kr <= qg) ? s0 : -1e30f;
                s1 = (k0 + 32 + kr <= qg) ? s1 : -1e30f;
            }
            st0[r] = s0; st1[r] = s1;
        }

        // ---- online softmax (per-lane q), T13 defer-max ----
        float v = st0[0];
        #pragma unroll
        for (int r = 1; r < 16; r++) v = fmaxf(v, st0[r]);
        #pragma unroll
        for (int r = 0; r < 16; r++) v = fmaxf(v, st1[r]);
        v = fmaxf(v, __shfl_xor(v, 32));
        if (__any(v > rowmax + 8.0f)) {
            const float mn = fmaxf(rowmax, v);
            const float fac = __expf(rowmax - mn);
            rowmax = mn;
            rowsum *= fac;
            #pragma unroll
            for (int r = 0; r < 16; r++) {
                const float facr = __shfl(fac, (r & 3) + 8 * (r >> 2) + 4 * hi);
                #pragma unroll
                for (int dt = 0; dt < 4; dt++) acc[dt][r] *= facr;
            }
        }
        float ss = 0.f;
        #pragma unroll
        for (int r = 0; r < 16; r++) {
            const float p0 = __expf(st0[r] - rowmax);
            const float p1 = __expf(st1[r] - rowmax);
            st0[r] = p0; st1[r] = p1;
            ss += p0 + p1;
        }
        ss += __shfl_xor(ss, 32);
        rowsum += ss;

        // ---- pack P into PV A-frags (in-register, one shfl per dword pair) ----
        unsigned int p0k[8], p1k[8];
        #pragma unroll
        for (int i = 0; i < 8; i++) {
            p0k[i] = pkbf(st0[2 * i], st0[2 * i + 1]);
            p1k[i] = pkbf(st1[2 * i], st1[2 * i + 1]);
        }
        bf16x8 pa[4];
        #pragma unroll
        for (int kt = 0; kt < 2; kt++) {
            const unsigned int* pk = kt ? p1k : p0k;
            const unsigned int sv1 = __shfl_xor((int)(hi ? pk[0] : pk[2]), 32);
            const unsigned int sv2 = __shfl_xor((int)(hi ? pk[1] : pk[3]), 32);
            const unsigned int sv3 = __shfl_xor((int)(hi ? pk[4] : pk[6]), 32);
            const unsigned int sv4 = __shfl_xor((int)(hi ? pk[5] : pk[7]), 32);
            u32x4 ulo, uhi2;
            ulo[0] = hi ? sv1 : pk[0];
            ulo[1] = hi ? sv2 : pk[1];
            ulo[2] = hi ? pk[2] : sv1;
            ulo[3] = hi ? pk[3] : sv2;
            uhi2[0] = hi ? sv3 : pk[4];
            uhi2[1] = hi ? sv4 : pk[5];
            uhi2[2] = hi ? pk[6] : sv3;
            uhi2[3] = hi ? pk[7] : sv4;
            pa[kt * 2]     = __builtin_bit_cast(bf16x8, ulo);
            pa[kt * 2 + 1] = __builtin_bit_cast(bf16x8, uhi2);
        }

        // ---- PV: acc[dt] += P(32q x 16k) x V(16k x 32d), 4 k-steps ----
        #pragma unroll
        for (int dt = 0; dt < 4; dt++) {
            #pragma unroll
            for (int s = 0; s < 4; s++) {
                const bf16x8 vf = *(const bf16x8*)(Vs + (dt * 32 + l31) * 64 + (((2 * s + hi) ^ (l31 & 7)) << 3));
                acc[dt] = __builtin_amdgcn_mfma_f32_32x32x16_bf16(pa[s], vf, acc[dt], 0, 0, 0);
            }
        }
        __syncthreads();
    }

    // ---- write O: D[q][d]: d = l31, q = (r&3)+8*(r>>2)+4*hi ----
    #pragma unroll
    for (int r = 0; r < 16; r++) {
        const int qr = (r & 3) + 8 * (r >> 2) + 4 * hi;
        const float inv = 1.0f / __shfl(rowsum, qr);
        bf16* orow = O + ((size_t)(b * S_ + q0 + qr)) * (H_ * HD_) + h * HD_ + l31;
        #pragma unroll
        for (int dt = 0; dt < 4; dt++)
            orow[dt * 32] = (bf16)(acc[dt][r] * inv);
    }
}

// ---------------- launch ----------------

extern "C" void kernel_launch(void* const* d_in, const int* in_sizes, int n_in,
                              void* d_out, int out_size, void* d_ws, size_t ws_size,
                              hipStream_t stream) {
    const float* x  = (const float*)d_in[0];
    const float* Wq = (const float*)d_in[1];
    const float* Wk = (const float*)d_in[2];
    const float* Wv = (const float*)d_in[3];
    const float* Wo = (const float*)d_in[4];
    float* out = (float*)d_out;

    const size_t NX   = (size_t)B_ * S_ * D_;
    const size_t NQKVW= (size_t)QKVS * D_;
    const size_t NQKV = (size_t)B_ * S_ * QKVS;
    const size_t NWK  = (size_t)D_ * HKV_ * HD_;

    bf16* p = (bf16*)d_ws;
    bf16* xb    = p;  p += NX;
    bf16* WqkvT = p;  p += NQKVW;
    bf16* QKV   = p;  p += NQKV;
    bf16* Ab  = xb;
    bf16* Vtb = WqkvT;
    bf16* WoT = WqkvT + NWK;

    // prep: cast x; build WqkvT = [WqT; WkT; WvT]  (64x64 vectorized transpose)
    cast_f32_bf16_kernel<<<(int)(NX / 1024), 256, 0, stream>>>(x, xb, (int)NX);
    transpose_cast_kernel<<<dim3((H_ * HD_) / 64, D_ / 64), 256, 0, stream>>>(Wq, WqkvT, D_, H_ * HD_);
    transpose_cast_kernel<<<dim3((HKV_ * HD_) / 64, D_ / 64), 256, 0, stream>>>(Wk, WqkvT + (size_t)(H_ * HD_) * D_, D_, HKV_ * HD_);
    transpose_cast_kernel<<<dim3((HKV_ * HD_) / 64, D_ / 64), 256, 0, stream>>>(Wv, WqkvT + (size_t)(H_ * HD_ + HKV_ * HD_) * D_, D_, HKV_ * HD_);

    // Q projection: 256 blocks (perfect single round), write QKV cols 0..4095
    gemm_bt256_kernel<bf16><<<256, 512, 0, stream>>>(xb, WqkvT, QKV, B_ * S_, H_ * HD_, D_, QKVS);
    // KV projection: 128^2 kernel, 512 blocks, write QKV cols 4096..6143
    gemm_bt_kernel<bf16><<<dim3(32, 16), 256, 0, stream>>>(xb, WqkvT + (size_t)(H_ * HD_) * D_,
                                                           QKV + H_ * HD_, B_ * S_, QKVS, D_);

    // rope on K only (Q rope fused into attention prologue)
    rope_kernel<<<B_ * S_, 256, 0, stream>>>(QKV + H_ * HD_, HKV_, QKVS);

    // V transpose (V = cols 5120.. of QKV): 64x64 vectorized
    transpose_v_kernel<<<dim3(HD_ / 64, S_ / 64, B_ * HKV_), 256, 0, stream>>>(QKV + H_ * HD_ + HKV_ * HD_, Vtb);

    // attention: Q (un-roped, rotated in-kernel) at QKV col 0, K at col 4096
    attn_kernel<<<1024, 256, 0, stream>>>(QKV, QKV + H_ * HD_, Vtb, Ab);

    // output projection
    transpose_cast_kernel<<<dim3(D_ / 64, (H_ * HD_) / 64), 256, 0, stream>>>(Wo, WoT, H_ * HD_, D_);
    gemm_bt256_kernel<float><<<256, 512, 0, stream>>>(Ab, WoT, out, B_ * S_, D_, H_ * HD_, D_);
}

// Round 25
// 563.295 us; speedup vs baseline: 1.0062x; 1.0062x over previous
//
#include <hip/hip_runtime.h>
#include <hip/hip_bf16.h>

// Problem constants
#define B_   2
#define S_   2048
#define D_   4096
#define H_   32
#define HKV_ 8
#define HD_  128
#define QKVS 6144   // fused QKV row stride (H*HD + 2*HKV*HD)

typedef __bf16 bf16;
typedef __bf16 bf16x8 __attribute__((ext_vector_type(8)));
typedef __bf16 bf16x4 __attribute__((ext_vector_type(4)));
typedef __bf16 bf16x2 __attribute__((ext_vector_type(2)));
typedef float  f32x4  __attribute__((ext_vector_type(4)));
typedef float  f32x16 __attribute__((ext_vector_type(16)));
typedef unsigned int u32x4 __attribute__((ext_vector_type(4)));

// ---------------- prep kernels ----------------

__global__ void cast_f32_bf16_kernel(const float* __restrict__ in, bf16* __restrict__ out, int n) {
    int i = (blockIdx.x * blockDim.x + threadIdx.x) * 4;
    if (i >= n) return;
    const float4 v = *(const float4*)(in + i);
    bf16x4 o;
    o[0] = (bf16)v.x; o[1] = (bf16)v.y; o[2] = (bf16)v.z; o[3] = (bf16)v.w;
    *(bf16x4*)(out + i) = o;
}

// W: K x N fp32 row-major -> WT: N x K bf16 row-major. 64x64 tile, 256 thr.
__global__ __launch_bounds__(256) void transpose_cast_kernel(const float* __restrict__ W,
                                                             bf16* __restrict__ WT, int K, int N) {
    __shared__ bf16 t[64][65];
    const int n0 = blockIdx.x * 64, k0 = blockIdx.y * 64;
    const int tx = threadIdx.x & 15, ty = threadIdx.x >> 4;   // 16 x 16
    #pragma unroll
    for (int i = 0; i < 4; i++) {
        const float4 v = *(const float4*)(W + (size_t)(k0 + ty + i * 16) * N + n0 + tx * 4);
        t[ty + i * 16][tx * 4 + 0] = (bf16)v.x;
        t[ty + i * 16][tx * 4 + 1] = (bf16)v.y;
        t[ty + i * 16][tx * 4 + 2] = (bf16)v.z;
        t[ty + i * 16][tx * 4 + 3] = (bf16)v.w;
    }
    __syncthreads();
    #pragma unroll
    for (int i = 0; i < 4; i++) {
        bf16x4 o;
        #pragma unroll
        for (int j = 0; j < 4; j++) o[j] = t[tx * 4 + j][ty + i * 16];
        *(bf16x4*)(WT + (size_t)(n0 + ty + i * 16) * K + k0 + tx * 4) = o;
    }
}

// V (cols 5120.. of QKV, row stride QKVS) -> Vt: (b,hk,d) x s bf16. 64x64 tile.
__global__ __launch_bounds__(256) void transpose_v_kernel(const bf16* __restrict__ V,
                                                          bf16* __restrict__ Vt) {
    __shared__ bf16 t[64][65];
    const int bh = blockIdx.z;            // b*HKV + hk
    const int b = bh >> 3, hk = bh & 7;
    const int d0 = blockIdx.x * 64, s0 = blockIdx.y * 64;
    const int tx = threadIdx.x & 15, ty = threadIdx.x >> 4;
    #pragma unroll
    for (int i = 0; i < 4; i++) {
        const bf16x4 v = *(const bf16x4*)(V + (size_t)(b * S_ + s0 + ty + i * 16) * QKVS + hk * HD_ + d0 + tx * 4);
        #pragma unroll
        for (int j = 0; j < 4; j++) t[ty + i * 16][tx * 4 + j] = v[j];   // t[s][d]
    }
    __syncthreads();
    #pragma unroll
    for (int i = 0; i < 4; i++) {
        bf16x4 o;
        #pragma unroll
        for (int j = 0; j < 4; j++) o[j] = t[tx * 4 + j][ty + i * 16];
        *(bf16x4*)(Vt + (size_t)(bh * HD_ + d0 + ty + i * 16) * S_ + s0 + tx * 4) = o;
    }
}

// rotate-half RoPE in place; Q (32 heads) + K (8 heads) contiguous -> nh=40.
__global__ void rope_kernel(bf16* __restrict__ T, int nh, int stride) {
    const int row = blockIdx.x;
    const int pos = row & (S_ - 1);
    const size_t base = (size_t)row * stride;
    const int npairs = nh * 64;
    const float c = 13.287712379549449f / 64.0f;   // log2(10000)/64
    for (int p = threadIdx.x; p < npairs; p += blockDim.x) {
        const int h = p >> 6, d = p & 63;
        const float invf = exp2f(-(float)d * c);
        const float ang = (float)pos * invf;
        float sn, cs;
        sincosf(ang, &sn, &cs);
        const size_t i1 = base + (size_t)h * HD_ + d;
        const size_t i2 = i1 + 64;
        const float a  = (float)T[i1];
        const float b2 = (float)T[i2];
        T[i1] = (bf16)(a * cs - b2 * sn);
        T[i2] = (bf16)(b2 * cs + a * sn);
    }
}

__device__ __forceinline__ void gload_lds16(const bf16* g, bf16* l) {
    __builtin_amdgcn_global_load_lds((const __attribute__((address_space(1))) void*)g,
                                     (__attribute__((address_space(3))) void*)l, 16, 0, 0);
}

// ---------------- GEMM 128x128 (m97 structure) — KV projection ----------------

template <typename CT>
__global__ __launch_bounds__(256) void gemm_bt_kernel(const bf16* __restrict__ A,
                                                      const bf16* __restrict__ Bm,
                                                      CT* __restrict__ C,
                                                      int M, int Cs, int K) {
    __shared__ bf16 As[128 * 32];
    __shared__ bf16 Bs[128 * 32];
    const int m0 = blockIdx.x * 128, n0 = blockIdx.y * 128;
    const int tid = threadIdx.x;
    const int lane = tid & 63, wid = tid >> 6;
    const int wm = wid >> 1, wn = wid & 1;       // 2x2 waves -> 64x64 each
    const int lg = lane >> 4, lr = lane & 15;
    f32x4 acc[4][4] = {};
    const int arow = tid >> 2;
    const int achunk = (tid & 3) * 8;
    for (int k0 = 0; k0 < K; k0 += 32) {
        gload_lds16(A  + (size_t)(m0 + arow) * K      + k0 + achunk, As + tid * 8);
        gload_lds16(A  + (size_t)(m0 + 64 + arow) * K + k0 + achunk, As + 2048 + tid * 8);
        gload_lds16(Bm + (size_t)(n0 + arow) * K      + k0 + achunk, Bs + tid * 8);
        gload_lds16(Bm + (size_t)(n0 + 64 + arow) * K + k0 + achunk, Bs + 2048 + tid * 8);
        __syncthreads();
        bf16x8 af[4], bfv[4];
        #pragma unroll
        for (int i = 0; i < 4; i++) {
            af[i]  = *(const bf16x8*)(As + (wm * 64 + i * 16 + lr) * 32 + lg * 8);
            bfv[i] = *(const bf16x8*)(Bs + (wn * 64 + i * 16 + lr) * 32 + lg * 8);
        }
        #pragma unroll
        for (int mi = 0; mi < 4; mi++)
            #pragma unroll
            for (int ni = 0; ni < 4; ni++)
                acc[mi][ni] = __builtin_amdgcn_mfma_f32_16x16x32_bf16(af[mi], bfv[ni], acc[mi][ni], 0, 0, 0);
        __syncthreads();
    }
    #pragma unroll
    for (int mi = 0; mi < 4; mi++)
        #pragma unroll
        for (int ni = 0; ni < 4; ni++)
            #pragma unroll
            for (int r = 0; r < 4; r++) {
                const int row = m0 + wm * 64 + mi * 16 + lg * 4 + r;
                const int col = n0 + wn * 64 + ni * 16 + lr;
                C[(size_t)row * Cs + col] = (CT)acc[mi][ni][r];
            }
}

// ---------------- GEMM 256x256, BK=64, 8 waves, 4-phase pipelined + quadrant reg-cache ----

template <typename CT>
__global__ __launch_bounds__(512, 2) void gemm_bt256_kernel(const bf16* __restrict__ A,
                                                            const bf16* __restrict__ Bm,
                                                            CT* __restrict__ C,
                                                            int M, int N, int K, int Cs) {
    __shared__ bf16 sm[65536];   // 128 KiB
    const int nbx = N >> 8;
    const int cpx = gridDim.x >> 3;
    const int bid = blockIdx.x;
    const int swz = (bid & 7) * cpx + (bid >> 3);       // XCD swizzle (grid % 8 == 0)
    const int m0 = (swz / nbx) << 8;
    const int n0 = (swz % nbx) << 8;

    const int tid = threadIdx.x;
    const int w = tid >> 6, lane = tid & 63;
    const int wm = w >> 2, wn = w & 3;                  // 2 x 4 wave grid, 128x64 per wave
    const int lg = lane >> 4, lr = lane & 15;
    const int nkt = K >> 6;

    const bf16* Ab = A + (size_t)m0 * K;
    const bf16* Bb = Bm + (size_t)n0 * K;

    const int u8 = tid >> 3;
    const int schunk = ((tid & 7) ^ (u8 & 7)) << 3;     // pre-swizzled source col offset

    auto stageA = [&](int buf, int kt, int h) {
        bf16* dst = sm + buf * 32768 + h * 4096 + tid * 8;
        const bf16* src = Ab + (size_t)(h * 64 + u8) * K + kt * 64 + schunk;
        gload_lds16(src, dst);
        gload_lds16(src + (size_t)128 * K, dst + 8192);
    };
    auto stageB = [&](int buf, int kt, int h) {
        bf16* dst = sm + buf * 32768 + 16384 + h * 2048 + ((u8 >> 5) << 12) + ((u8 & 31) << 6) + ((tid & 7) << 3);
        const bf16* src = Bb + (size_t)(h * 32 + ((u8 >> 5) << 6) + (u8 & 31)) * K + kt * 64 + schunk;
        gload_lds16(src, dst);
        gload_lds16(src + (size_t)128 * K, dst + 8192);
    };

    f32x4 acc[8][4] = {};

    // prologue: tile0 fully -> buf0 (8 loads); tile1 B0,A0 -> buf1 (4 loads)
    stageA(0, 0, 0); stageA(0, 0, 1); stageB(0, 0, 0); stageB(0, 0, 1);
    stageB(1, 1, 0); stageA(1, 1, 0);
    asm volatile("s_waitcnt vmcnt(4)" ::: "memory");    // tile0 landed; tile1's 4 in flight
    __builtin_amdgcn_s_barrier();

    #define MFMA_Q(MI0, NI0, AREG, BREG)                                                     \
        __builtin_amdgcn_s_setprio(1);                                                       \
        _Pragma("unroll") for (int i = 0; i < 4; ++i)                                        \
            _Pragma("unroll") for (int i2 = 0; i2 < 2; ++i2)                                 \
                _Pragma("unroll") for (int kk = 0; kk < 2; ++kk)                             \
                    acc[MI0 + i][NI0 + i2] = __builtin_amdgcn_mfma_f32_16x16x32_bf16(        \
                        AREG[i][kk], BREG[i2][kk], acc[MI0 + i][NI0 + i2], 0, 0, 0);         \
        __builtin_amdgcn_s_setprio(0);                                                       \
        __builtin_amdgcn_s_barrier();

    #define SYNC_IN()                                                                        \
        __builtin_amdgcn_s_barrier();                                                        \
        asm volatile("s_waitcnt lgkmcnt(0)" ::: "memory");                                   \
        __builtin_amdgcn_sched_barrier(0);

    for (int t = 0; t < nkt; ++t) {
        const int cur = t & 1;
        const bf16* curA = sm + cur * 32768;
        const bf16* curB = curA + 16384;
        bf16x8 afc[4][2], b0[2][2], b1[2][2];

        // ---- Phase A: (0,0). Read+cache A-quad0, B-quad0. Stage A1(t+1)->other.
        #pragma unroll
        for (int i = 0; i < 4; ++i) {
            const int row = wm * 128 + i * 16 + lr;
            #pragma unroll
            for (int kk = 0; kk < 2; ++kk)
                afc[i][kk] = *(const bf16x8*)(curA + row * 64 + (((kk * 4 + lg) ^ (lr & 7)) << 3));
        }
        #pragma unroll
        for (int i2 = 0; i2 < 2; ++i2) {
            const int row = wn * 64 + i2 * 16 + lr;
            #pragma unroll
            for (int kk = 0; kk < 2; ++kk)
                b0[i2][kk] = *(const bf16x8*)(curB + row * 64 + (((kk * 4 + lg) ^ (lr & 7)) << 3));
        }
        if (t + 1 < nkt) stageA(cur ^ 1, t + 1, 1);
        if (t + 1 == nkt) asm volatile("s_waitcnt vmcnt(0)" ::: "memory");  // final-tile drain
        SYNC_IN()
        MFMA_Q(0, 0, afc, b0)

        // ---- Phase B: (0,1). Read+cache B-quad1. Stage B1(t+1)->other.
        #pragma unroll
        for (int i2 = 0; i2 < 2; ++i2) {
            const int row = wn * 64 + (2 + i2) * 16 + lr;
            #pragma unroll
            for (int kk = 0; kk < 2; ++kk)
                b1[i2][kk] = *(const bf16x8*)(curB + row * 64 + (((kk * 4 + lg) ^ (lr & 7)) << 3));
        }
        if (t + 1 < nkt) stageB(cur ^ 1, t + 1, 1);
        SYNC_IN()
        MFMA_Q(0, 2, afc, b1)

        // ---- Phase C: (1,0). Read A-quad1 (overwrite cache); b0 still cached. Stage B0(t+2)->cur.
        #pragma unroll
        for (int i = 0; i < 4; ++i) {
            const int row = wm * 128 + (4 + i) * 16 + lr;
            #pragma unroll
            for (int kk = 0; kk < 2; ++kk)
                afc[i][kk] = *(const bf16x8*)(curA + row * 64 + (((kk * 4 + lg) ^ (lr & 7)) << 3));
        }
        if (t + 2 < nkt) stageB(cur, t + 2, 0);
        SYNC_IN()
        MFMA_Q(4, 0, afc, b0)

        // ---- Phase D: (1,1). No LDS reads (afc=A1, b1 cached). Stage A0(t+2)->cur; counted wait.
        if (t + 2 < nkt) stageA(cur, t + 2, 0);
        asm volatile("s_waitcnt vmcnt(4)" ::: "memory");
        SYNC_IN()
        MFMA_Q(4, 2, afc, b1)
    }
    #undef MFMA_Q
    #undef SYNC_IN

    #pragma unroll
    for (int mi = 0; mi < 8; ++mi)
        #pragma unroll
        for (int ni = 0; ni < 4; ++ni)
            #pragma unroll
            for (int r = 0; r < 4; ++r) {
                const int row = m0 + wm * 128 + mi * 16 + lg * 4 + r;
                const int col = n0 + wn * 64 + ni * 16 + lr;
                C[(size_t)row * Cs + col] = (CT)acc[mi][ni][r];
            }
}

// ---------------- flash attention — 32x32x16 MFMA, swapped QK^T, in-register P ----------------
// (round-19/23 proven form)
#define KVB_ 64

__device__ __forceinline__ unsigned int pkbf(float lo, float hi2) {
    bf16x2 t; t[0] = (bf16)lo; t[1] = (bf16)hi2;
    return __builtin_bit_cast(unsigned int, t);
}

__global__ __launch_bounds__(256) void attn_kernel(const bf16* __restrict__ Q,
                                                   const bf16* __restrict__ Kb,
                                                   const bf16* __restrict__ Vt,
                                                   bf16* __restrict__ O) {
    __shared__ bf16 lds[16384];   // Ks[64][128] | Vs[128][64]  (32 KiB)
    bf16* Ks = lds;
    bf16* Vs = lds + 8192;

    const int flat = blockIdx.x;
    const int x = flat & 7;
    const int j = flat >> 3;
    const int hkb = x * 2 + (j & 1);
    const int qt = 63 - (j >> 1);
    const int hk = hkb & 7, b = hkb >> 3;
    const int q0 = qt * 32;

    const int tid = threadIdx.x;
    const int w = tid >> 6, lane = tid & 63;
    const int l31 = lane & 31, hi = lane >> 5;
    const int h = hk * 4 + w;

    // Q fragments (B-operand): col q = q0+l31, hd = t*16 + hi*8 + j
    const bf16* qrow = Q + ((size_t)(b * S_ + q0 + l31)) * QKVS + h * HD_ + hi * 8;
    bf16x8 qf[8];
    #pragma unroll
    for (int t = 0; t < 8; t++) qf[t] = *(const bf16x8*)(qrow + t * 16);

    const bf16* Kh = Kb + ((size_t)b * S_) * QKVS + hk * HD_;
    const bf16* Vh = Vt + ((size_t)(b * HKV_ + hk)) * HD_ * S_;

    const int krow_s  = tid >> 4;
    const int kchnk_s = (tid & 15) ^ (tid >> 4);
    const int vrow_s  = tid >> 3;
    const int vchnk_s = (tid & 7) ^ ((tid >> 3) & 7);

    f32x16 acc[4];
    #pragma unroll
    for (int dt = 0; dt < 4; dt++) acc[dt] = (f32x16)(0.f);
    float rowmax = -1e30f, rowsum = 0.f;

    const float scale = 0.08838834764831845f;
    const int nt = (q0 + 32 + KVB_ - 1) / KVB_;
    const int qg = q0 + l31;

    for (int it = 0; it < nt; ++it) {
        const int k0 = it * KVB_;
        #pragma unroll
        for (int jj = 0; jj < 4; jj++)
            gload_lds16(Kh + (size_t)(k0 + jj * 16 + krow_s) * QKVS + kchnk_s * 8,
                        Ks + jj * 2048 + tid * 8);
        #pragma unroll
        for (int jj = 0; jj < 4; jj++)
            gload_lds16(Vh + (size_t)(jj * 32 + vrow_s) * S_ + k0 + vchnk_s * 8,
                        Vs + jj * 2048 + tid * 8);
        __syncthreads();

        // ---- QK^T swapped: st0/st1 = mfma(K_sub, Q) -> D[k][q=l31] ----
        f32x16 st0 = (f32x16)(0.f), st1 = (f32x16)(0.f);
        #pragma unroll
        for (int t = 0; t < 8; t++) {
            const int ch = (((2 * t + hi) ^ (l31 & 15)) << 3);
            const bf16x8 kf0 = *(const bf16x8*)(Ks + l31 * 128 + ch);
            const bf16x8 kf1 = *(const bf16x8*)(Ks + (32 + l31) * 128 + ch);
            st0 = __builtin_amdgcn_mfma_f32_32x32x16_bf16(kf0, qf[t], st0, 0, 0, 0);
            st1 = __builtin_amdgcn_mfma_f32_32x32x16_bf16(kf1, qf[t], st1, 0, 0, 0);
        }

        // ---- scale + causal mask: k = k0 + kt*32 + (r&3)+8*(r>>2)+4*hi, q = qg ----
        const bool need_mask = (k0 + KVB_ - 1 > q0);
        #pragma unroll
        for (int r = 0; r < 16; r++) {
            const int kr = (r & 3) + 8 * (r >> 2) + 4 * hi;
            float s0 = st0[r] * scale;
            float s1 = st1[r] * scale;
            if (need_mask) {
                s0 = (k0 + kr <= qg) ? s0 : -1e30f;
                s1 = (k0 + 32 + kr <= qg) ? s1 : -1e30f;
            }
            st0[r] = s0; st1[r] = s1;
        }

        // ---- online softmax (per-lane q), T13 defer-max ----
        float v = st0[0];
        #pragma unroll
        for (int r = 1; r < 16; r++) v = fmaxf(v, st0[r]);
        #pragma unroll
        for (int r = 0; r < 16; r++) v = fmaxf(v, st1[r]);
        v = fmaxf(v, __shfl_xor(v, 32));
        if (__any(v > rowmax + 8.0f)) {
            const float mn = fmaxf(rowmax, v);
            const float fac = __expf(rowmax - mn);
            rowmax = mn;
            rowsum *= fac;
            #pragma unroll
            for (int r = 0; r < 16; r++) {
                const float facr = __shfl(fac, (r & 3) + 8 * (r >> 2) + 4 * hi);
                #pragma unroll
                for (int dt = 0; dt < 4; dt++) acc[dt][r] *= facr;
            }
        }
        float ss = 0.f;
        #pragma unroll
        for (int r = 0; r < 16; r++) {
            const float p0 = __expf(st0[r] - rowmax);
            const float p1 = __expf(st1[r] - rowmax);
            st0[r] = p0; st1[r] = p1;
            ss += p0 + p1;
        }
        ss += __shfl_xor(ss, 32);
        rowsum += ss;

        // ---- pack P into PV A-frags (in-register, one shfl per dword pair) ----
        unsigned int p0k[8], p1k[8];
        #pragma unroll
        for (int i = 0; i < 8; i++) {
            p0k[i] = pkbf(st0[2 * i], st0[2 * i + 1]);
            p1k[i] = pkbf(st1[2 * i], st1[2 * i + 1]);
        }
        bf16x8 pa[4];
        #pragma unroll
        for (int kt = 0; kt < 2; kt++) {
            const unsigned int* pk = kt ? p1k : p0k;
            const unsigned int sv1 = __shfl_xor((int)(hi ? pk[0] : pk[2]), 32);
            const unsigned int sv2 = __shfl_xor((int)(hi ? pk[1] : pk[3]), 32);
            const unsigned int sv3 = __shfl_xor((int)(hi ? pk[4] : pk[6]), 32);
            const unsigned int sv4 = __shfl_xor((int)(hi ? pk[5] : pk[7]), 32);
            u32x4 ulo, uhi2;
            ulo[0] = hi ? sv1 : pk[0];
            ulo[1] = hi ? sv2 : pk[1];
            ulo[2] = hi ? pk[2] : sv1;
            ulo[3] = hi ? pk[3] : sv2;
            uhi2[0] = hi ? sv3 : pk[4];
            uhi2[1] = hi ? sv4 : pk[5];
            uhi2[2] = hi ? pk[6] : sv3;
            uhi2[3] = hi ? pk[7] : sv4;
            pa[kt * 2]     = __builtin_bit_cast(bf16x8, ulo);
            pa[kt * 2 + 1] = __builtin_bit_cast(bf16x8, uhi2);
        }

        // ---- PV: acc[dt] += P(32q x 16k) x V(16k x 32d), 4 k-steps ----
        #pragma unroll
        for (int dt = 0; dt < 4; dt++) {
            #pragma unroll
            for (int s = 0; s < 4; s++) {
                const bf16x8 vf = *(const bf16x8*)(Vs + (dt * 32 + l31) * 64 + (((2 * s + hi) ^ (l31 & 7)) << 3));
                acc[dt] = __builtin_amdgcn_mfma_f32_32x32x16_bf16(pa[s], vf, acc[dt], 0, 0, 0);
            }
        }
        __syncthreads();
    }

    // ---- write O: D[q][d]: d = l31, q = (r&3)+8*(r>>2)+4*hi ----
    #pragma unroll
    for (int r = 0; r < 16; r++) {
        const int qr = (r & 3) + 8 * (r >> 2) + 4 * hi;
        const float inv = 1.0f / __shfl(rowsum, qr);
        bf16* orow = O + ((size_t)(b * S_ + q0 + qr)) * (H_ * HD_) + h * HD_ + l31;
        #pragma unroll
        for (int dt = 0; dt < 4; dt++)
            orow[dt * 32] = (bf16)(acc[dt][r] * inv);
    }
}

// ---------------- launch ----------------

extern "C" void kernel_launch(void* const* d_in, const int* in_sizes, int n_in,
                              void* d_out, int out_size, void* d_ws, size_t ws_size,
                              hipStream_t stream) {
    const float* x  = (const float*)d_in[0];
    const float* Wq = (const float*)d_in[1];
    const float* Wk = (const float*)d_in[2];
    const float* Wv = (const float*)d_in[3];
    const float* Wo = (const float*)d_in[4];
    float* out = (float*)d_out;

    const size_t NX   = (size_t)B_ * S_ * D_;
    const size_t NQKVW= (size_t)QKVS * D_;
    const size_t NQKV = (size_t)B_ * S_ * QKVS;
    const size_t NWK  = (size_t)D_ * HKV_ * HD_;

    bf16* p = (bf16*)d_ws;
    bf16* xb    = p;  p += NX;
    bf16* WqkvT = p;  p += NQKVW;
    bf16* QKV   = p;  p += NQKV;
    bf16* Ab  = xb;
    bf16* Vtb = WqkvT;
    bf16* WoT = WqkvT + NWK;

    // prep: cast x; build WqkvT = [WqT; WkT; WvT]  (64x64 vectorized transpose)
    cast_f32_bf16_kernel<<<(int)(NX / 1024), 256, 0, stream>>>(x, xb, (int)NX);
    transpose_cast_kernel<<<dim3((H_ * HD_) / 64, D_ / 64), 256, 0, stream>>>(Wq, WqkvT, D_, H_ * HD_);
    transpose_cast_kernel<<<dim3((HKV_ * HD_) / 64, D_ / 64), 256, 0, stream>>>(Wk, WqkvT + (size_t)(H_ * HD_) * D_, D_, HKV_ * HD_);
    transpose_cast_kernel<<<dim3((HKV_ * HD_) / 64, D_ / 64), 256, 0, stream>>>(Wv, WqkvT + (size_t)(H_ * HD_ + HKV_ * HD_) * D_, D_, HKV_ * HD_);

    // Q projection: 256 blocks (perfect single round), write QKV cols 0..4095
    gemm_bt256_kernel<bf16><<<256, 512, 0, stream>>>(xb, WqkvT, QKV, B_ * S_, H_ * HD_, D_, QKVS);
    // KV projection: 128^2 kernel, 512 blocks, write QKV cols 4096..6143
    gemm_bt_kernel<bf16><<<dim3(32, 16), 256, 0, stream>>>(xb, WqkvT + (size_t)(H_ * HD_) * D_,
                                                           QKV + H_ * HD_, B_ * S_, QKVS, D_);

    // rope on Q+K together (heads 0..39 contiguous at cols 0..5119)
    rope_kernel<<<B_ * S_, 256, 0, stream>>>(QKV, H_ + HKV_, QKVS);

    // V transpose (V = cols 5120.. of QKV): 64x64 vectorized
    transpose_v_kernel<<<dim3(HD_ / 64, S_ / 64, B_ * HKV_), 256, 0, stream>>>(QKV + H_ * HD_ + HKV_ * HD_, Vtb);

    // attention: Q at QKV col 0, K at col 4096; both stride QKVS
    attn_kernel<<<1024, 256, 0, stream>>>(QKV, QKV + H_ * HD_, Vtb, Ab);

    // output projection
    transpose_cast_kernel<<<dim3(D_ / 64, (H_ * HD_) / 64), 256, 0, stream>>>(Wo, WoT, H_ * HD_, D_);
    gemm_bt256_kernel<float><<<256, 512, 0, stream>>>(Ab, WoT, out, B_ * S_, D_, H_ * HD_, D_);
}